// Round 9
// baseline (249.886 us; speedup 1.0000x reference)
//
#include <hip/hip_runtime.h>
#include <stdint.h>

// ---------------------------------------------------------------------------
// RLMALinear: out = x @ (alpha*R + U@V)^T + bias
//   x: [32,4096,512] f32, U: [512,64] f32, V: [64,512] f32, bias: [512] f32
// Stage 1: build W (bf16) in d_ws via threefry2x32 + erfinv.
// Stage 2 (R8): W-STATIONARY, A-LDS-FREE.
//   Block = 128 out-cols x 1024 m-rows (4 m-iters of 256). W panel 128x512
//   bf16 = 128 KB LDS, granule-XOR-swizzled (conflict-free b128 reads),
//   staged ONCE via global_load_lds (one barrier per kernel).
//   x streams global->VGPR (1 cache line per row per step) with a 4-deep
//   static register pipeline, cvt_pk to bf16, 32x32x16 MFMA (4x output per
//   instr -> half the LDS reads per output vs 16x16). No A staging at all.
// ---------------------------------------------------------------------------

#define M_TOTAL 131072
#define N_DIM 512
#define K_DIM 512
#define RANK 64

#define BN_BLK 128   // out-cols per block
#define MI_ROWS 256  // m-rows per m-iter (8 waves x 32)
#define MT 4         // m-iters per block -> 1024 rows per block

typedef __attribute__((ext_vector_type(8))) short bf16x8;
typedef __attribute__((ext_vector_type(16))) float f32x16;

// ---- JAX threefry2x32 -----------------------------------------------------
__device__ __forceinline__ void threefry2x32(uint32_t k0, uint32_t k1,
                                             uint32_t x0, uint32_t x1,
                                             uint32_t& y0, uint32_t& y1) {
  uint32_t ks2 = k0 ^ k1 ^ 0x1BD11BDAu;
  const uint32_t ks[3] = {k0, k1, ks2};
  const int R0[4] = {13, 15, 26, 6};
  const int R1[4] = {17, 29, 16, 24};
  x0 += ks[0];
  x1 += ks[1];
#pragma unroll
  for (int g = 0; g < 5; ++g) {
    const int* r = (g & 1) ? R1 : R0;
#pragma unroll
    for (int i = 0; i < 4; ++i) {
      x0 += x1;
      x1 = (x1 << r[i]) | (x1 >> (32 - r[i]));
      x1 ^= x0;
    }
    x0 += ks[(g + 1) % 3];
    x1 += ks[(g + 2) % 3] + (uint32_t)(g + 1);
  }
  y0 = x0;
  y1 = x1;
}

// ---- XLA ErfInv32 (Giles 2012) --------------------------------------------
__device__ __forceinline__ float erfinv_f32(float x) {
  float w = -log1pf(-x * x);
  float p;
  if (w < 5.0f) {
    w = w - 2.5f;
    p = 2.81022636e-08f;
    p = fmaf(p, w, 3.43273939e-07f);
    p = fmaf(p, w, -3.5233877e-06f);
    p = fmaf(p, w, -4.39150654e-06f);
    p = fmaf(p, w, 0.00021858087f);
    p = fmaf(p, w, -0.00125372503f);
    p = fmaf(p, w, -0.00417768164f);
    p = fmaf(p, w, 0.246640727f);
    p = fmaf(p, w, 1.50140941f);
  } else {
    w = sqrtf(w) - 3.0f;
    p = -0.000200214257f;
    p = fmaf(p, w, 0.000100950558f);
    p = fmaf(p, w, 0.00134934322f);
    p = fmaf(p, w, -0.00367342844f);
    p = fmaf(p, w, 0.00573950773f);
    p = fmaf(p, w, -0.0076224613f);
    p = fmaf(p, w, 0.00943887047f);
    p = fmaf(p, w, 1.00167406f);
    p = fmaf(p, w, 2.83297682f);
  }
  return p * x;
}

__device__ __forceinline__ unsigned short f32_to_bf16_rtne(float f) {
  uint32_t x = __float_as_uint(f);
  uint32_t r = (x + 0x7FFFu + ((x >> 16) & 1u)) >> 16;
  return (unsigned short)r;
}

// ---- Stage 1 --------------------------------------------------------------
__global__ __launch_bounds__(256) void build_w_kernel(
    const float* __restrict__ alpha_p, const float* __restrict__ U,
    const float* __restrict__ V, const int* __restrict__ k_iter_p,
    unsigned short* __restrict__ Wb) {
  int idx = blockIdx.x * blockDim.x + threadIdx.x;
  uint32_t s = (1234u ^ (uint32_t)(*k_iter_p));
  uint32_t y0, y1;
  threefry2x32(0u, s, 0u, (uint32_t)idx, y0, y1);
  uint32_t bits = y0 ^ y1;
  float u01 = __uint_as_float((bits >> 9) | 0x3f800000u) - 1.0f;
  const float lo = -0.99999994f;
  float u = fmaxf(lo, u01 * 2.0f + lo);
  float rnorm = 1.41421354f * erfinv_f32(u);
  const float scale = 0.044194173824159216f;  // fp32(1/sqrt(512))

  int o = idx >> 9;
  int i = idx & 511;
  float uv = 0.0f;
#pragma unroll 8
  for (int r = 0; r < RANK; ++r)
    uv = fmaf(U[o * RANK + r], V[r * N_DIM + i], uv);

  float w = (*alpha_p) * (rnorm * scale) + uv;
  Wb[idx] = f32_to_bf16_rtne(w);
}

// ---- async 16B global->LDS ------------------------------------------------
__device__ __forceinline__ void gload16(const void* g, void* l) {
  __builtin_amdgcn_global_load_lds(
      (const __attribute__((address_space(1))) void*)g,
      (__attribute__((address_space(3))) void*)l, 16, 0, 0);
}

__device__ __forceinline__ bf16x8 cvt8(const float4& lo, const float4& hi) {
  union {
    bf16x8 v;
    uint32_t d[4];
  } au;
  asm("v_cvt_pk_bf16_f32 %0, %1, %2" : "=v"(au.d[0]) : "v"(lo.x), "v"(lo.y));
  asm("v_cvt_pk_bf16_f32 %0, %1, %2" : "=v"(au.d[1]) : "v"(lo.z), "v"(lo.w));
  asm("v_cvt_pk_bf16_f32 %0, %1, %2" : "=v"(au.d[2]) : "v"(hi.x), "v"(hi.y));
  asm("v_cvt_pk_bf16_f32 %0, %1, %2" : "=v"(au.d[3]) : "v"(hi.z), "v"(hi.w));
  return au.v;
}

// ---- Stage 2: GEMM --------------------------------------------------------
__global__ __launch_bounds__(512, 2) void gemm_kernel(
    const float* __restrict__ X, const unsigned short* __restrict__ Wb,
    const float* __restrict__ bias, float* __restrict__ Out) {
  extern __shared__ char smem[];  // W panel: 128 rows x 64 granules of 16B

  const int tid = threadIdx.x;
  const int lane = tid & 63;
  const int wave = tid >> 6;  // 0..7: each wave owns 32 m-rows, all 128 cols
  // grid 512 = 8 XCD x 64: the 4 nb-sharers of an x-panel are co-XCD adjacent
  const int p = blockIdx.x;
  const int l = (p & 7) * 64 + (p >> 3);
  const int nb = l & 3;
  const int mg = l >> 2;  // 0..127, each covers 1024 m-rows
  const int n0 = nb * BN_BLK;

  // ---- stage W panel once, granule-swizzled ----
  // LDS slot s: row = s>>6, pos = s&63 holds global granule pos^(row&7).
  // slot = c*512+tid -> row = c*8+wave, pos = lane; one full row per
  // wave-instr (perfectly coalesced, XOR-permuted within the 1KB row).
#pragma unroll
  for (int c = 0; c < 16; ++c) {
    int slot = c * 512 + tid;
    int row = slot >> 6;
    int g16 = (slot & 63) ^ (row & 7);
    gload16(Wb + (size_t)(n0 + row) * K_DIM + g16 * 8, smem + slot * 16);
  }
  __syncthreads();  // the only barrier in this kernel

  const int mr = lane & 31;  // m-row within wave tile / B col / D col
  const int kh = lane >> 5;  // k-half
  // W read, step s, colfrag cf: row = cf*32+mr, granule g16 = 2s+kh,
  // stored at pos = g16 ^ (row&7). (2s|kh)^e == (2s)^(kh^e) (bit-disjoint).
  const int kev = kh ^ (lane & 7);
  int baseW[4];
#pragma unroll
  for (int cf = 0; cf < 4; ++cf) baseW[cf] = (cf * 32 + mr) * 1024;

  // x: row = mg*1024 + mt*256 + wave*32 + mr; step s reads 32B at s*64+kh*32
  const char* xp = (const char*)X +
                   ((size_t)mg * 1024 + wave * 32 + mr) * (K_DIM * 4) + kh * 32;

  for (int mt = 0; mt < MT; ++mt) {
    f32x16 acc[4];
#pragma unroll
    for (int cf = 0; cf < 4; ++cf)
#pragma unroll
      for (int q = 0; q < 16; ++q) acc[cf][q] = 0.0f;

    // 4-deep static register pipeline for x (32 steps, 32%4==0)
    float4 xq[4][2];
#pragma unroll
    for (int s = 0; s < 4; ++s) {
      xq[s][0] = *reinterpret_cast<const float4*>(xp + s * 64);
      xq[s][1] = *reinterpret_cast<const float4*>(xp + s * 64 + 16);
    }

#pragma unroll
    for (int s = 0; s < 32; ++s) {
      bf16x8 xa = cvt8(xq[s & 3][0], xq[s & 3][1]);
      if (s < 28) {  // refill slot with step s+4
        xq[s & 3][0] = *reinterpret_cast<const float4*>(xp + (s + 4) * 64);
        xq[s & 3][1] = *reinterpret_cast<const float4*>(xp + (s + 4) * 64 + 16);
      }
#pragma unroll
      for (int cf = 0; cf < 4; ++cf) {
        bf16x8 wf = *reinterpret_cast<const bf16x8*>(
            smem + baseW[cf] + (((2 * s) ^ kev) << 4));
        acc[cf] = __builtin_amdgcn_mfma_f32_32x32x16_bf16(wf, xa, acc[cf],
                                                          0, 0, 0);
      }
    }

    // ---- epilogue. D: col(lane&31)=m-row, row=(q&3)+8*(q>>2)+4*kh = n-col
    const size_t mrow = (size_t)mg * 1024 + mt * 256 + wave * 32 + mr;
    float* orow = Out + mrow * N_DIM;
#pragma unroll
    for (int cf = 0; cf < 4; ++cf) {
#pragma unroll
      for (int t = 0; t < 4; ++t) {
        const int col = n0 + cf * 32 + t * 8 + kh * 4;
        float4 bv = *reinterpret_cast<const float4*>(bias + col);
        float4 o;
        o.x = acc[cf][4 * t + 0] + bv.x;
        o.y = acc[cf][4 * t + 1] + bv.y;
        o.z = acc[cf][4 * t + 2] + bv.z;
        o.w = acc[cf][4 * t + 3] + bv.w;
        *reinterpret_cast<float4*>(orow + col) = o;
      }
    }

    xp += (size_t)MI_ROWS * (K_DIM * 4);
  }
}

extern "C" void kernel_launch(void* const* d_in, const int* in_sizes, int n_in,
                              void* d_out, int out_size, void* d_ws,
                              size_t ws_size, hipStream_t stream) {
  (void)in_sizes;
  (void)n_in;
  (void)out_size;
  (void)ws_size;
  const float* x = (const float*)d_in[0];
  const float* alpha = (const float*)d_in[1];
  const float* U = (const float*)d_in[2];
  const float* V = (const float*)d_in[3];
  const float* bias = (const float*)d_in[4];
  const int* k_iter = (const int*)d_in[5];
  float* out = (float*)d_out;
  unsigned short* Wb = (unsigned short*)d_ws;  // 512 KiB scratch

  build_w_kernel<<<(N_DIM * K_DIM) / 256, 256, 0, stream>>>(alpha, U, V,
                                                            k_iter, Wb);

  const int lds_bytes = BN_BLK * K_DIM * 2;  // 131072
  hipFuncSetAttribute((const void*)gemm_kernel,
                      hipFuncAttributeMaxDynamicSharedMemorySize, lds_bytes);
  const int grid = (N_DIM / BN_BLK) * (M_TOTAL / (MI_ROWS * MT));  // 4*128=512
  gemm_kernel<<<grid, 512, lds_bytes, stream>>>(x, Wb, bias, out);
}

// Round 10
// 188.874 us; speedup vs baseline: 1.3230x; 1.3230x over previous
//
#include <hip/hip_runtime.h>
#include <stdint.h>

// ---------------------------------------------------------------------------
// RLMALinear: out = x @ (alpha*R + U@V)^T + bias
// Stage 1: build W (bf16) in d_ws via threefry2x32 + erfinv.
// Stage 2 (R10 = R1 + 2-deep register prefetch):
//   128x128 tile, 256 thr, BK=64, single-LDS-buffer with 2 barriers/step,
//   reg-staged bf16 A (cvt_pk) + bf16 W. Register staging double-buffered:
//   ISSUE(kt+2) during compute(kt), WRITE_LDS(kt+1) after the read barrier.
//   In-flight staged tiles ~= resident_blocks(2.5) x depth(2) -> covers the
//   ~10-12K-cycle loaded HBM latency that R5/R6/R7 exposed (model fit R1-R8).
// ---------------------------------------------------------------------------

#define M_TOTAL 131072
#define N_DIM 512
#define K_DIM 512
#define RANK 64

typedef __attribute__((ext_vector_type(8))) short bf16x8;
typedef __attribute__((ext_vector_type(4))) float f32x4;

// ---- JAX threefry2x32 -----------------------------------------------------
__device__ __forceinline__ void threefry2x32(uint32_t k0, uint32_t k1,
                                             uint32_t x0, uint32_t x1,
                                             uint32_t& y0, uint32_t& y1) {
  uint32_t ks2 = k0 ^ k1 ^ 0x1BD11BDAu;
  const uint32_t ks[3] = {k0, k1, ks2};
  const int R0[4] = {13, 15, 26, 6};
  const int R1[4] = {17, 29, 16, 24};
  x0 += ks[0];
  x1 += ks[1];
#pragma unroll
  for (int g = 0; g < 5; ++g) {
    const int* r = (g & 1) ? R1 : R0;
#pragma unroll
    for (int i = 0; i < 4; ++i) {
      x0 += x1;
      x1 = (x1 << r[i]) | (x1 >> (32 - r[i]));
      x1 ^= x0;
    }
    x0 += ks[(g + 1) % 3];
    x1 += ks[(g + 2) % 3] + (uint32_t)(g + 1);
  }
  y0 = x0;
  y1 = x1;
}

// ---- XLA ErfInv32 (Giles 2012) --------------------------------------------
__device__ __forceinline__ float erfinv_f32(float x) {
  float w = -log1pf(-x * x);
  float p;
  if (w < 5.0f) {
    w = w - 2.5f;
    p = 2.81022636e-08f;
    p = fmaf(p, w, 3.43273939e-07f);
    p = fmaf(p, w, -3.5233877e-06f);
    p = fmaf(p, w, -4.39150654e-06f);
    p = fmaf(p, w, 0.00021858087f);
    p = fmaf(p, w, -0.00125372503f);
    p = fmaf(p, w, -0.00417768164f);
    p = fmaf(p, w, 0.246640727f);
    p = fmaf(p, w, 1.50140941f);
  } else {
    w = sqrtf(w) - 3.0f;
    p = -0.000200214257f;
    p = fmaf(p, w, 0.000100950558f);
    p = fmaf(p, w, 0.00134934322f);
    p = fmaf(p, w, -0.00367342844f);
    p = fmaf(p, w, 0.00573950773f);
    p = fmaf(p, w, -0.0076224613f);
    p = fmaf(p, w, 0.00943887047f);
    p = fmaf(p, w, 1.00167406f);
    p = fmaf(p, w, 2.83297682f);
  }
  return p * x;
}

__device__ __forceinline__ unsigned short f32_to_bf16_rtne(float f) {
  uint32_t x = __float_as_uint(f);
  uint32_t r = (x + 0x7FFFu + ((x >> 16) & 1u)) >> 16;
  return (unsigned short)r;
}

// ---- Stage 1 --------------------------------------------------------------
__global__ __launch_bounds__(256) void build_w_kernel(
    const float* __restrict__ alpha_p, const float* __restrict__ U,
    const float* __restrict__ V, const int* __restrict__ k_iter_p,
    unsigned short* __restrict__ Wb) {
  int idx = blockIdx.x * blockDim.x + threadIdx.x;
  uint32_t s = (1234u ^ (uint32_t)(*k_iter_p));
  uint32_t y0, y1;
  threefry2x32(0u, s, 0u, (uint32_t)idx, y0, y1);
  uint32_t bits = y0 ^ y1;
  float u01 = __uint_as_float((bits >> 9) | 0x3f800000u) - 1.0f;
  const float lo = -0.99999994f;
  float u = fmaxf(lo, u01 * 2.0f + lo);
  float rnorm = 1.41421354f * erfinv_f32(u);
  const float scale = 0.044194173824159216f;  // fp32(1/sqrt(512))

  int o = idx >> 9;
  int i = idx & 511;
  float uv = 0.0f;
#pragma unroll 8
  for (int r = 0; r < RANK; ++r)
    uv = fmaf(U[o * RANK + r], V[r * N_DIM + i], uv);

  float w = (*alpha_p) * (rnorm * scale) + uv;
  Wb[idx] = f32_to_bf16_rtne(w);
}

// ---- Stage 2: GEMM out[m][n] = sum_k x[m][k] * W[n][k] + bias[n] ----------
#define BM 128
#define BN 128
#define BK 64
#define LDK 72  // +8 bf16 pad
#define NSTEP 8

__global__ __launch_bounds__(256, 2) void gemm_kernel(
    const float* __restrict__ X, const unsigned short* __restrict__ Wb,
    const float* __restrict__ bias, float* __restrict__ Out) {
  __shared__ unsigned short As[BM][LDK];
  __shared__ unsigned short Bs[BN][LDK];

  const int tid = threadIdx.x;
  // XCD swizzle: grid 4096 = 8 XCDs x 512; 4 nb-sharers adjacent per XCD.
  const int p = blockIdx.x;
  const int l = (p & 7) * 512 + (p >> 3);
  const int nb = l & 3;
  const int mb = l >> 2;
  const int m0 = mb * BM;
  const int n0 = nb * BN;

  const int lane = tid & 63;
  const int wave = tid >> 6;  // 4 waves, 2x2 -> each owns 64x64
  const int wr = wave >> 1;
  const int wc = wave & 1;

  f32x4 acc[4][4];
#pragma unroll
  for (int i = 0; i < 4; ++i)
#pragma unroll
    for (int j = 0; j < 4; ++j) acc[i][j] = (f32x4){0.f, 0.f, 0.f, 0.f};

  // X staging map: thread t, iter j: row=(t>>4)+j*16, 4 floats at (t&15)*4
  const int xr = tid >> 4;
  const int xc = (tid & 15) * 4;
  // W staging map: thread t, iter j: row=(t>>3)+j*32, 8 bf16 at (t&7)*8
  const int wrow = tid >> 3;
  const int wcol = (tid & 7) * 8;

  // 2-deep register staging: slot = kt & 1
  float4 xv[2][8];
  bf16x8 wv[2][4];

#define ISSUE_LOADS(kt_, s_)                                               \
  {                                                                        \
    const int k0_ = (kt_)*BK;                                              \
    _Pragma("unroll") for (int j = 0; j < 8; ++j) xv[s_][j] =              \
        *reinterpret_cast<const float4*>(                                  \
            &X[(size_t)(m0 + xr + j * 16) * K_DIM + k0_ + xc]);            \
    _Pragma("unroll") for (int j = 0; j < 4; ++j) wv[s_][j] =              \
        *reinterpret_cast<const bf16x8*>(                                  \
            &Wb[(size_t)(n0 + wrow + j * 32) * K_DIM + k0_ + wcol]);       \
  }

#define WRITE_LDS(s_)                                                      \
  {                                                                        \
    _Pragma("unroll") for (int j = 0; j < 8; ++j) {                        \
      uint32_t p0_, p1_;                                                   \
      asm("v_cvt_pk_bf16_f32 %0, %1, %2"                                   \
          : "=v"(p0_)                                                      \
          : "v"(xv[s_][j].x), "v"(xv[s_][j].y));                           \
      asm("v_cvt_pk_bf16_f32 %0, %1, %2"                                   \
          : "=v"(p1_)                                                      \
          : "v"(xv[s_][j].z), "v"(xv[s_][j].w));                           \
      uint2 pk_;                                                           \
      pk_.x = p0_;                                                         \
      pk_.y = p1_;                                                         \
      *reinterpret_cast<uint2*>(&As[xr + j * 16][xc]) = pk_;               \
    }                                                                      \
    _Pragma("unroll") for (int j = 0; j < 4; ++j)                          \
        *reinterpret_cast<bf16x8*>(&Bs[wrow + j * 32][wcol]) = wv[s_][j];  \
  }

  // prologue: tiles 0 and 1 in flight; tile 0 into LDS
  ISSUE_LOADS(0, 0)
  ISSUE_LOADS(1, 1)
  WRITE_LDS(0)
  __syncthreads();

#pragma unroll
  for (int kt = 0; kt < NSTEP; ++kt) {
    // refill the slot just consumed-to-LDS with tile kt+2
    if (kt < NSTEP - 2) ISSUE_LOADS(kt + 2, kt & 1)

    // compute tile kt from LDS
#pragma unroll
    for (int ks = 0; ks < 2; ++ks) {
      bf16x8 a[4], b[4];
#pragma unroll
      for (int i = 0; i < 4; ++i)
        a[i] = *reinterpret_cast<const bf16x8*>(
            &As[wr * 64 + i * 16 + (lane & 15)][ks * 32 + (lane >> 4) * 8]);
#pragma unroll
      for (int j = 0; j < 4; ++j)
        b[j] = *reinterpret_cast<const bf16x8*>(
            &Bs[wc * 64 + j * 16 + (lane & 15)][ks * 32 + (lane >> 4) * 8]);
#pragma unroll
      for (int i = 0; i < 4; ++i)
#pragma unroll
        for (int j = 0; j < 4; ++j)
          acc[i][j] = __builtin_amdgcn_mfma_f32_16x16x32_bf16(a[i], b[j],
                                                              acc[i][j], 0, 0, 0);
    }
    __syncthreads();  // all waves done reading LDS

    if (kt < NSTEP - 1) {
      WRITE_LDS((kt + 1) & 1)  // vmcnt auto-wait on tile kt+1 only
      __syncthreads();
    }
  }

  // epilogue: C mapping col=lane&15, row=(lane>>4)*4+q
  const int col = lane & 15;
  const int rbase = (lane >> 4) * 4;
#pragma unroll
  for (int j = 0; j < 4; ++j) {
    int oc = n0 + wc * 64 + j * 16 + col;
    float bv = bias[oc];
#pragma unroll
    for (int i = 0; i < 4; ++i) {
      int orow = m0 + wr * 64 + i * 16 + rbase;
#pragma unroll
      for (int q = 0; q < 4; ++q) {
        Out[(size_t)(orow + q) * N_DIM + oc] = acc[i][j][q] + bv;
      }
    }
  }
#undef ISSUE_LOADS
#undef WRITE_LDS
}

extern "C" void kernel_launch(void* const* d_in, const int* in_sizes, int n_in,
                              void* d_out, int out_size, void* d_ws,
                              size_t ws_size, hipStream_t stream) {
  (void)in_sizes;
  (void)n_in;
  (void)out_size;
  (void)ws_size;
  const float* x = (const float*)d_in[0];
  const float* alpha = (const float*)d_in[1];
  const float* U = (const float*)d_in[2];
  const float* V = (const float*)d_in[3];
  const float* bias = (const float*)d_in[4];
  const int* k_iter = (const int*)d_in[5];
  float* out = (float*)d_out;
  unsigned short* Wb = (unsigned short*)d_ws;  // 512 KiB scratch

  build_w_kernel<<<(N_DIM * K_DIM) / 256, 256, 0, stream>>>(alpha, U, V,
                                                            k_iter, Wb);
  const int grid = (M_TOTAL / BM) * (N_DIM / BN);  // 4096
  gemm_kernel<<<grid, 256, 0, stream>>>(x, Wb, bias, out);
}